// Round 12
// baseline (179.546 us; speedup 1.0000x reference)
//
#include <hip/hip_runtime.h>

#define N_GENE 4762
#define N_CELL 847
#define NEDGE  200000
#define D      256
#define NPART  64     // hist/scatter chunks
#define MAGIC  0x7A3B9C1D

typedef __attribute__((ext_vector_type(8))) short short8;            // 8 bf16
typedef __attribute__((ext_vector_type(8))) unsigned short ushort8v; // 16B load
typedef __attribute__((ext_vector_type(4))) float f32x4;

// ---- histogram segment layout (bins, concatenated) ----
#define S_G_OUT 0                      // [4762] g2c_src degrees (genes)
#define S_C_IN  (S_G_OUT + N_GENE)     // [847]  g2c_dst degrees (cells)
#define S_C_OUT (S_C_IN + N_CELL)      // [847]  c2g_src degrees (cells)
#define S_G_IN  (S_C_OUT + N_CELL)     // [4762] c2g_dst degrees (genes)
#define NBINS   (S_G_IN + N_GENE)      // 11218

#define ALIGN8(x) (((x) + 7) & ~7)

// ---- workspace layout (4-byte slots) ----
#define A_DEG      0                          // int[11218]
#define A_NRM      (A_DEG + NBINS)            // float[11218]
#define A_OFFS_C   (A_NRM + NBINS)            // int[848]
#define A_OFFS_G   (A_OFFS_C + N_CELL + 1)    // int[4763]
#define A_SORT_C   ALIGN8(A_OFFS_G + N_GENE + 1) // int2[200000]
#define A_SORT_G   (A_SORT_C + 2 * NEDGE)     // int2[200000]
#define A_PART     (A_SORT_G + 2 * NEDGE)     // int[64*11218]
#define A_SG       (A_PART + NPART * NBINS)   // float[4762]
#define A_SC       (A_SG + N_GENE)            // float[847]
#define A_FLAGS    ALIGN8(A_SC + N_CELL)      // int[640]: 0..255 hist, 256..266 reduce, 267..617 gemm
// bf16 regions (ushort; slot = count/2), 16B-aligned
#define A_GENE_BF  ALIGN8(A_FLAGS + 640)
#define A_CELL_BF  ALIGN8(A_GENE_BF + N_GENE * D / 2)
#define A_WT1_BF   ALIGN8(A_CELL_BF + N_CELL * D / 2)
#define A_WT2_BF   ALIGN8(A_WT1_BF + D * D / 2)
#define A_AGGC_BF  ALIGN8(A_WT2_BF + D * D / 2)
#define A_AGGG_BF  ALIGN8(A_AGGC_BF + N_CELL * D / 2)

__device__ __forceinline__ unsigned short f2bf(float f) {
    unsigned u = __float_as_uint(f);
    u = (u + 0x7FFFu + ((u >> 16) & 1u)) >> 16;    // RNE
    return (unsigned short)u;
}
__device__ __forceinline__ float bf2f(unsigned short b) {
    return __uint_as_float(((unsigned)b) << 16);
}

// Producer signal: caller must have passed __syncthreads() (drains all waves'
// vmcnt). T==0 does release-fence (writes back L2) + relaxed MAGIC store.
__device__ __forceinline__ void sig(int* slot) {
    __builtin_amdgcn_fence(__ATOMIC_RELEASE, "agent");
    __hip_atomic_store(slot, MAGIC, __ATOMIC_RELAXED, __HIP_MEMORY_SCOPE_AGENT);
}
// Consumer wait: thread t polls slots[t], t+stride, ... (relaxed loads only),
// then __syncthreads + acquire-fence (one cache-inv per wave, no RMWs).
// Timeout-hardened: graceful wrong answer instead of hang.
__device__ __forceinline__ void waitflags(const int* slots, int n, int T, int nthr) {
    for (int s = T; s < n; s += nthr) {
        long long t0 = (long long)__builtin_amdgcn_s_memrealtime();
        while (__hip_atomic_load(&slots[s], __ATOMIC_RELAXED,
                                 __HIP_MEMORY_SCOPE_AGENT) != MAGIC) {
            __builtin_amdgcn_s_sleep(2);
            if ((long long)__builtin_amdgcn_s_memrealtime() - t0 > 50000000LL) break;
        }
    }
    __syncthreads();
    __builtin_amdgcn_fence(__ATOMIC_ACQUIRE, "agent");
}

// K1: fused front-end, flag-ordered phases, 459 blocks x 1024 (all resident):
//   blocks 0..255   hist (4-way segment split, LDS 19KB)   -> sig(flags[B])
//   blocks 256..319 cvt + W^T + zero sg/sc                  (no deps)
//   blocks 320..330 wait(hist,256) -> reduce               -> sig(flags[256+i])
//   blocks 331..458 wait(reduce,11) -> counting sort (R0 scan + rank seeds)
__global__ __launch_bounds__(1024) void k_front(
        const int* __restrict__ g2c_src, const int* __restrict__ g2c_dst,
        const int* __restrict__ c2g_src, const int* __restrict__ c2g_dst,
        const float* __restrict__ gene_emb, const float* __restrict__ cell_emb,
        const float* __restrict__ W_g2c, const float* __restrict__ W_c2g,
        int* __restrict__ partial, int* __restrict__ deg, float* __restrict__ nrm,
        int* __restrict__ offsC, int* __restrict__ offsG,
        int2* __restrict__ sortC, int2* __restrict__ sortG,
        unsigned short* __restrict__ gene_bf, unsigned short* __restrict__ cell_bf,
        unsigned short* __restrict__ wt1, unsigned short* __restrict__ wt2,
        float* __restrict__ sg, float* __restrict__ sc,
        int* __restrict__ flags) {
    __shared__ int shm[2 * N_GENE + 24];   // hist: [0..4761]; scatter: soffs+scur+wsum
    int B = blockIdx.x, T = threadIdx.x;

    if (B < 4 * NPART) {
        // ---------------- hist ----------------
        int grp = B >> 6, blk = B & (NPART - 1);
        const int* idx;
        int segbase, segn;
        if      (grp == 0) { idx = g2c_src; segbase = S_G_OUT; segn = N_GENE; }
        else if (grp == 1) { idx = g2c_dst; segbase = S_C_IN;  segn = N_CELL; }
        else if (grp == 2) { idx = c2g_src; segbase = S_C_OUT; segn = N_CELL; }
        else               { idx = c2g_dst; segbase = S_G_IN;  segn = N_GENE; }
        for (int j = T; j < segn; j += 1024) shm[j] = 0;
        __syncthreads();
        const int chunk = (NEDGE + NPART - 1) / NPART;
        int e0 = blk * chunk, e1 = min(NEDGE, e0 + chunk);
        for (int e = e0 + T; e < e1; e += 1024) atomicAdd(&shm[idx[e]], 1);
        __syncthreads();
        int* pp = partial + blk * NBINS + segbase;
        for (int j = T; j < segn; j += 1024) pp[j] = shm[j];
        __syncthreads();                   // drain all waves' stores
        if (T == 0) sig(&flags[B]);
    } else if (B < 4 * NPART + 64) {
        // ---------------- cvt + W^T + zero ----------------
        const int NG = N_GENE * D, NC = N_CELL * D, NW = D * D;
        int base = (B - 4 * NPART) * 1024 + T;
        const int CH = (NG + NC) / 8;          // 8-elem chunks
        for (int c = base; c < CH; c += 64 * 1024) {
            const float* sp;
            unsigned short* dp;
            if (c < NG / 8) { sp = gene_emb + c * 8; dp = gene_bf + c * 8; }
            else { int j = (c - NG / 8) * 8; sp = cell_emb + j; dp = cell_bf + j; }
            f32x4 x0 = *(const f32x4*)sp;
            f32x4 x1 = *(const f32x4*)(sp + 4);
            ushort8v o;
            o[0] = f2bf(x0[0]); o[1] = f2bf(x0[1]);
            o[2] = f2bf(x0[2]); o[3] = f2bf(x0[3]);
            o[4] = f2bf(x1[0]); o[5] = f2bf(x1[1]);
            o[6] = f2bf(x1[2]); o[7] = f2bf(x1[3]);
            *(ushort8v*)dp = o;
        }
        for (int i = base; i < 2 * NW; i += 64 * 1024) {
            if (i < NW) {
                wt1[i] = f2bf(W_g2c[(i & 255) * D + (i >> 8)]);
            } else {
                int j = i - NW;
                wt2[j] = f2bf(W_c2g[(j & 255) * D + (j >> 8)]);
            }
        }
        for (int i = base; i < N_GENE + N_CELL; i += 64 * 1024) {
            if (i < N_GENE) sg[i] = 0.f; else sc[i - N_GENE] = 0.f;
        }
    } else if (B < 4 * NPART + 64 + 11) {
        // ---------------- reduce (after hist flags) ----------------
        waitflags(flags, 256, T, 1024);
        int j = (B - (4 * NPART + 64)) * 1024 + T;
        if (j < NBINS) {
            int s = 0;
            #pragma unroll
            for (int b0 = 0; b0 < NPART; b0 += 32) {
                int t[32];
                #pragma unroll
                for (int u = 0; u < 32; u++) t[u] = partial[(b0 + u) * NBINS + j];
                #pragma unroll
                for (int u = 0; u < 32; u++) { partial[(b0 + u) * NBINS + j] = s; s += t[u]; }
            }
            deg[j] = s;
            nrm[j] = rsqrtf(fmaxf((float)s, 1.0f));
        }
        __syncthreads();                   // drain all waves' stores
        if (T == 0) sig(&flags[256 + (B - (4 * NPART + 64))]);
    } else {
        // ---------------- counting sort (after reduce flags) ----------------
        waitflags(flags + 256, 11, T, 1024);
        int idx2 = B - (4 * NPART + 64 + 11);
        int blk = idx2 & (NPART - 1), dir = idx2 >> 6;
        int* soffs = shm;                        // [N_GENE+1]
        int* scur  = shm + N_GENE + 1;           // [N_GENE]
        int* wsum  = shm + 2 * N_GENE + 1;       // [16]
        const int* src  = dir ? c2g_src : g2c_src;
        const int* dst  = dir ? c2g_dst : g2c_dst;
        const int* dgs  = dir ? deg + S_G_IN : deg + S_C_IN;
        const float* nsv = dir ? nrm + S_C_OUT : nrm + S_G_OUT;
        int seg         = dir ? S_G_IN : S_C_IN;
        int nb          = dir ? N_GENE : N_CELL;
        int* goffs      = dir ? offsG : offsC;
        int2* sorted    = dir ? sortG : sortC;
        int per = (nb + 1023) >> 10;              // <=5
        int i0 = T * per, i1 = min(nb, i0 + per);
        int loc[5];
        int s = 0;
        for (int i = i0; i < i1; i++) { loc[i - i0] = s; s += dgs[i]; }
        int lane = T & 63, w = T >> 6;
        int t = s;
        #pragma unroll
        for (int off = 1; off < 64; off <<= 1) {
            int u = __shfl_up(t, off);
            if (lane >= off) t += u;
        }
        if (lane == 63) wsum[w] = t;
        __syncthreads();
        if (w == 0 && lane < 16) {
            int x = wsum[lane];
            #pragma unroll
            for (int off = 1; off < 16; off <<= 1) {
                int u = __shfl_up(x, off);
                if (lane >= off) x += u;
            }
            wsum[lane] = x;
        }
        __syncthreads();
        int wbase = w ? wsum[w - 1] : 0;
        int excl = wbase + t - s;
        for (int i = i0; i < i1; i++) soffs[i] = excl + loc[i - i0];
        if (T == 1023) soffs[nb] = excl + s;
        __syncthreads();
        if (blk == 0)
            for (int j = T; j <= nb; j += 1024) goffs[j] = soffs[j];
        const int* basep = partial + blk * NBINS + seg;
        for (int j = T; j < nb; j += 1024) scur[j] = soffs[j] + basep[j];
        __syncthreads();
        const int chunk = (NEDGE + NPART - 1) / NPART;
        int e0 = blk * chunk, e1 = min(NEDGE, e0 + chunk);
        for (int e = e0 + T; e < e1; e += 1024) {
            int d = dst[e], sv = src[e];
            float nv = nsv[sv];
            int pos = atomicAdd(&scur[d], 1);
            sorted[pos] = make_int2(sv, __float_as_int(nv));
        }
    }
}

// K2: aggregation, wave-per-node, 16-deep paired-row 16B gathers (R8 verbatim).
__global__ __launch_bounds__(256) void k_agg(
        const unsigned short* __restrict__ gene_bf,
        const unsigned short* __restrict__ cell_bf,
        const int2* __restrict__ sortC, const int2* __restrict__ sortG,
        const int* __restrict__ offsC, const int* __restrict__ offsG,
        const float* __restrict__ nrm,
        unsigned short* __restrict__ aggC, unsigned short* __restrict__ aggG) {
    __shared__ int   sidx[4][64];
    __shared__ float snrm[4][64];
    const int CB = (N_CELL + 3) / 4;   // 212
    int w = threadIdx.x >> 6, lane = threadIdx.x & 63;
    int half = lane >> 5, li = lane & 31;
    int B = blockIdx.x;
    bool isCell = B < CB;

    int e0, e1, node;
    const unsigned short* emb;
    const int2* sorted;
    unsigned short* outp;
    int nseg;
    if (isCell) {
        node = B * 4 + w;
        if (node >= N_CELL) return;
        e0 = offsC[node]; e1 = offsC[node + 1];
        emb = gene_bf; sorted = sortC; outp = aggC; nseg = S_C_IN;
    } else {
        node = (B - CB) * 4 + w;
        if (node >= N_GENE) return;
        e0 = offsG[node]; e1 = offsG[node + 1];
        emb = cell_bf; sorted = sortG; outp = aggG; nseg = S_G_IN;
    }

    float acc[8];
    #pragma unroll
    for (int c = 0; c < 8; c++) acc[c] = 0.f;

    for (int base = e0; base < e1; base += 64) {
        int n = min(64, e1 - base);
        if (lane < n) {
            int2 pr = sorted[base + lane];
            sidx[w][lane] = pr.x;
            snrm[w][lane] = __int_as_float(pr.y);
        }
        // same-wave LDS write->read: program order, no barrier needed
        int i = 0;                                 // i indexes row-PAIRS
        for (; 2 * i + 32 <= n; i += 16) {         // 16 loads in flight
            ushort8v v[16];
            float nv[16];
            #pragma unroll
            for (int k = 0; k < 16; k++) {
                int jj = 2 * (i + k) + half;
                v[k] = *(const ushort8v*)&emb[sidx[w][jj] * D + li * 8];
                nv[k] = snrm[w][jj];
            }
            #pragma unroll
            for (int c = 0; c < 8; c++) {
                float s0 = 0.f;
                #pragma unroll
                for (int k = 0; k < 16; k++) s0 += bf2f(v[k][c]) * nv[k];
                acc[c] += s0;
            }
        }
        for (; 2 * i + 16 <= n; i += 8) {          // 8 loads in flight
            ushort8v v[8];
            float nv[8];
            #pragma unroll
            for (int k = 0; k < 8; k++) {
                int jj = 2 * (i + k) + half;
                v[k] = *(const ushort8v*)&emb[sidx[w][jj] * D + li * 8];
                nv[k] = snrm[w][jj];
            }
            #pragma unroll
            for (int c = 0; c < 8; c++) {
                float s0 = 0.f;
                #pragma unroll
                for (int k = 0; k < 8; k++) s0 += bf2f(v[k][c]) * nv[k];
                acc[c] += s0;
            }
        }
        for (; 2 * i + 8 <= n; i += 4) {
            int j0 = 2 * i + half, j1 = 2 * i + 2 + half;
            int j2 = 2 * i + 4 + half, j3 = 2 * i + 6 + half;
            ushort8v v0 = *(const ushort8v*)&emb[sidx[w][j0] * D + li * 8];
            ushort8v v1 = *(const ushort8v*)&emb[sidx[w][j1] * D + li * 8];
            ushort8v v2 = *(const ushort8v*)&emb[sidx[w][j2] * D + li * 8];
            ushort8v v3 = *(const ushort8v*)&emb[sidx[w][j3] * D + li * 8];
            float n0 = snrm[w][j0], n1 = snrm[w][j1];
            float n2 = snrm[w][j2], n3 = snrm[w][j3];
            #pragma unroll
            for (int c = 0; c < 8; c++)
                acc[c] += bf2f(v0[c]) * n0 + bf2f(v1[c]) * n1 +
                          bf2f(v2[c]) * n2 + bf2f(v3[c]) * n3;
        }
        int npair = (n + 1) >> 1;
        for (; i < npair; i++) {
            int jj = 2 * i + half;
            bool ok = jj < n;
            int idx = ok ? sidx[w][jj] : sidx[w][0];
            float nv = ok ? snrm[w][jj] : 0.f;
            ushort8v v = *(const ushort8v*)&emb[idx * D + li * 8];
            #pragma unroll
            for (int c = 0; c < 8; c++) acc[c] += bf2f(v[c]) * nv;
        }
    }
    #pragma unroll
    for (int c = 0; c < 8; c++) acc[c] += __shfl_xor(acc[c], 32);

    if (half == 0) {
        float ndv = nrm[nseg + node];
        ushort8v o;
        #pragma unroll
        for (int c = 0; c < 8; c++) o[c] = f2bf(acc[c] * ndv);
        *(ushort8v*)&outp[node * D + li * 8] = o;
    }
}

// K3: fused back-end, 479 blocks x 256 (all resident at ~5 blocks/CU):
//   blocks 0..350   MFMA GEMM N-split (R8 verbatim)        -> sig(flags[267+B])
//   blocks 351..478 wait(gemm,351) -> edge scores (grid-stride)
__global__ __launch_bounds__(256) void k_back(
        const unsigned short* __restrict__ aggC, const unsigned short* __restrict__ aggG,
        const unsigned short* __restrict__ wt1, const unsigned short* __restrict__ wt2,
        const float* __restrict__ b_g2c, const float* __restrict__ b_c2g,
        const float* __restrict__ Wp,
        float* __restrict__ hC, float* __restrict__ hG,
        float* __restrict__ sg, float* __restrict__ sc,
        const int* __restrict__ dsrc, const int* __restrict__ ddst,
        const float* __restrict__ bp, float* __restrict__ out,
        int* __restrict__ flags) {
    const int CT = (N_CELL + 15) / 16;   // 53
    const int GT = (N_GENE + 15) / 16;   // 298
    int B = blockIdx.x, T = threadIdx.x;
    if (B < CT + GT) {
        int wid = B * 4 + (T >> 6);       // < (CT+GT)*4 always
        int tid = wid >> 2, nq = wid & 3;
        int n0 = nq * 64;
        bool isCell = tid < CT;
        int tile = isCell ? tid : tid - CT;
        int m0 = tile * 16;
        int M = isCell ? N_CELL : N_GENE;
        const unsigned short* A  = isCell ? aggC : aggG;
        const unsigned short* Wt = isCell ? wt1 : wt2;
        const float* bias = isCell ? b_g2c : b_c2g;
        const float* wp   = isCell ? Wp + D : Wp;
        float* H  = isCell ? hC : hG;
        float* sv = isCell ? sc : sg;
        int lane = T & 63;
        int l15 = lane & 15, quad = lane >> 4;
        int arow = m0 + l15;
        if (arow >= M) arow = M - 1;
        f32x4 acc[4];
        #pragma unroll
        for (int t = 0; t < 4; t++) acc[t] = (f32x4){0.f, 0.f, 0.f, 0.f};
        #pragma unroll
        for (int k0 = 0; k0 < D; k0 += 32) {
            short8 a = *(const short8*)&A[arow * D + k0 + quad * 8];
            #pragma unroll
            for (int t = 0; t < 4; t++) {
                short8 b = *(const short8*)&Wt[(n0 + t * 16 + l15) * D + k0 + quad * 8];
                acc[t] = __builtin_amdgcn_mfma_f32_16x16x32_bf16(a, b, acc[t], 0, 0, 0);
            }
        }
        float dot[4] = {0.f, 0.f, 0.f, 0.f};
        #pragma unroll
        for (int t = 0; t < 4; t++) {
            int col = n0 + t * 16 + l15;
            float bv = bias[col], wv = wp[col];
            #pragma unroll
            for (int r = 0; r < 4; r++) {
                int row = m0 + quad * 4 + r;
                float h = fmaxf(acc[t][r] + bv, 0.f);
                if (row < M) H[row * D + col] = h;
                dot[r] += h * wv;
            }
        }
        #pragma unroll
        for (int off = 1; off < 16; off <<= 1) {
            #pragma unroll
            for (int r = 0; r < 4; r++) dot[r] += __shfl_xor(dot[r], off);
        }
        if (l15 == 0) {
            #pragma unroll
            for (int r = 0; r < 4; r++) {
                int row = m0 + quad * 4 + r;
                if (row < M) atomicAdd(&sv[row], dot[r]);
            }
        }
        __syncthreads();                   // drain all waves' stores/atomics
        if (T == 0) sig(&flags[267 + B]);
    } else {
        waitflags(flags + 267, CT + GT, T, 256);
        float bpv = bp[0];
        int i0 = (B - (CT + GT)) * 256 + T;
        for (int i = i0; i < NEDGE; i += 128 * 256)
            out[i] = sg[dsrc[i]] + sc[ddst[i]] + bpv;
    }
}

extern "C" void kernel_launch(void* const* d_in, const int* in_sizes, int n_in,
                              void* d_out, int out_size, void* d_ws, size_t ws_size,
                              hipStream_t stream) {
    const float* gene_emb = (const float*)d_in[0];
    const float* cell_emb = (const float*)d_in[1];
    const float* W_g2c    = (const float*)d_in[2];
    const float* b_g2c    = (const float*)d_in[3];
    const float* W_c2g    = (const float*)d_in[4];
    const float* b_c2g    = (const float*)d_in[5];
    const float* Wp       = (const float*)d_in[6];
    const float* bp       = (const float*)d_in[7];
    const int* g2c_src = (const int*)d_in[8];
    const int* g2c_dst = (const int*)d_in[9];
    const int* c2g_src = (const int*)d_in[10];
    const int* c2g_dst = (const int*)d_in[11];
    const int* dec_src = (const int*)d_in[12];
    const int* dec_dst = (const int*)d_in[13];

    int*   wsi = (int*)d_ws;
    float* wsf = (float*)d_ws;
    unsigned short* gene_bf = (unsigned short*)(wsi + A_GENE_BF);
    unsigned short* cell_bf = (unsigned short*)(wsi + A_CELL_BF);
    unsigned short* wt1     = (unsigned short*)(wsi + A_WT1_BF);
    unsigned short* wt2     = (unsigned short*)(wsi + A_WT2_BF);
    unsigned short* aggC    = (unsigned short*)(wsi + A_AGGC_BF);
    unsigned short* aggG    = (unsigned short*)(wsi + A_AGGG_BF);
    int2* sortC = (int2*)(wsi + A_SORT_C);
    int2* sortG = (int2*)(wsi + A_SORT_G);

    float* out = (float*)d_out;
    float* out_score = out;                      // [200000]
    float* out_hgene = out + NEDGE;              // [4762*256]
    float* out_hcell = out + NEDGE + N_GENE * D; // [847*256]

    // K1: hist || cvt -> (flag) reduce -> (flag) counting sort
    k_front<<<4 * NPART + 64 + 11 + 2 * NPART, 1024, 0, stream>>>(
        g2c_src, g2c_dst, c2g_src, c2g_dst, gene_emb, cell_emb, W_g2c, W_c2g,
        wsi + A_PART, wsi + A_DEG, wsf + A_NRM,
        wsi + A_OFFS_C, wsi + A_OFFS_G, sortC, sortG,
        gene_bf, cell_bf, wt1, wt2, wsf + A_SG, wsf + A_SC,
        wsi + A_FLAGS);
    // K2: aggregate (wave-per-node, best measured 18.1us)
    {
        const int CB = (N_CELL + 3) / 4, GB = (N_GENE + 3) / 4;
        k_agg<<<CB + GB, 256, 0, stream>>>(
            gene_bf, cell_bf, sortC, sortG, wsi + A_OFFS_C, wsi + A_OFFS_G,
            wsf + A_NRM, aggC, aggG);
    }
    // K3: MFMA GEMMs -> (flag) edge scores
    {
        const int CT = (N_CELL + 15) / 16, GT = (N_GENE + 15) / 16;
        k_back<<<CT + GT + 128, 256, 0, stream>>>(
            aggC, aggG, wt1, wt2, b_g2c, b_c2g, Wp,
            out_hcell, out_hgene, wsf + A_SG, wsf + A_SC,
            dec_src, dec_dst, bp, out_score, wsi + A_FLAGS);
    }
}

// Round 13
// 148.911 us; speedup vs baseline: 1.2057x; 1.2057x over previous
//
#include <hip/hip_runtime.h>

#define N_GENE 4762
#define N_CELL 847
#define NEDGE  200000
#define D      256
#define NPART  64     // hist/scatter chunks

typedef __attribute__((ext_vector_type(8))) short short8;            // 8 bf16
typedef __attribute__((ext_vector_type(8))) unsigned short ushort8v; // 16B load
typedef __attribute__((ext_vector_type(4))) float f32x4;

// ---- histogram segment layout (bins, concatenated) ----
#define S_G_OUT 0                      // [4762] g2c_src degrees (genes)
#define S_C_IN  (S_G_OUT + N_GENE)     // [847]  g2c_dst degrees (cells)
#define S_C_OUT (S_C_IN + N_CELL)      // [847]  c2g_src degrees (cells)
#define S_G_IN  (S_C_OUT + N_CELL)     // [4762] c2g_dst degrees (genes)
#define NBINS   (S_G_IN + N_GENE)      // 11218

#define ALIGN8(x) (((x) + 7) & ~7)

// ---- workspace layout (4-byte slots) ----
#define A_NRM      0                          // float[11218]
#define A_OFFS_C   (A_NRM + NBINS)            // int[848]
#define A_OFFS_G   (A_OFFS_C + N_CELL + 1)    // int[4763]
#define A_SORT_C   ALIGN8(A_OFFS_G + N_GENE + 1) // int2[200000]
#define A_SORT_G   (A_SORT_C + 2 * NEDGE)     // int2[200000]
#define A_PART     (A_SORT_G + 2 * NEDGE)     // int[64*11218] raw counts
#define A_SG       (A_PART + NPART * NBINS)   // float[4762]
#define A_SC       (A_SG + N_GENE)            // float[847]
// bf16 regions (ushort; slot = count/2), 16B-aligned
#define A_GENE_BF  ALIGN8(A_SC + N_CELL)
#define A_CELL_BF  ALIGN8(A_GENE_BF + N_GENE * D / 2)
#define A_WT1_BF   ALIGN8(A_CELL_BF + N_CELL * D / 2)
#define A_WT2_BF   ALIGN8(A_WT1_BF + D * D / 2)
#define A_AGGC_BF  ALIGN8(A_WT2_BF + D * D / 2)
#define A_AGGG_BF  ALIGN8(A_AGGC_BF + N_CELL * D / 2)

__device__ __forceinline__ unsigned short f2bf(float f) {
    unsigned u = __float_as_uint(f);
    u = (u + 0x7FFFu + ((u >> 16) & 1u)) >> 16;    // RNE
    return (unsigned short)u;
}
__device__ __forceinline__ float bf2f(unsigned short b) {
    return __uint_as_float(((unsigned)b) << 16);
}

// blocks 0..255: per-block LDS histograms, 4-way SEGMENT-SPLIT (verified R7):
//   group = B>>6 handles one segment (one index array), chunk = B&63.
// blocks 256..319: vectorized bf16 conversions + W transposes + sg/sc zeroing.
__global__ __launch_bounds__(1024) void k_pre(
        const int* __restrict__ g2c_src, const int* __restrict__ g2c_dst,
        const int* __restrict__ c2g_src, const int* __restrict__ c2g_dst,
        const float* __restrict__ gene_emb, const float* __restrict__ cell_emb,
        const float* __restrict__ W_g2c, const float* __restrict__ W_c2g,
        int* __restrict__ partial,
        unsigned short* __restrict__ gene_bf, unsigned short* __restrict__ cell_bf,
        unsigned short* __restrict__ wt1, unsigned short* __restrict__ wt2,
        float* __restrict__ sg, float* __restrict__ sc) {
    __shared__ int sh[N_GENE];          // max segment size
    int B = blockIdx.x, T = threadIdx.x;
    if (B < 4 * NPART) {
        int grp = B >> 6, blk = B & (NPART - 1);
        const int* idx;
        int segbase, segn;
        if      (grp == 0) { idx = g2c_src; segbase = S_G_OUT; segn = N_GENE; }
        else if (grp == 1) { idx = g2c_dst; segbase = S_C_IN;  segn = N_CELL; }
        else if (grp == 2) { idx = c2g_src; segbase = S_C_OUT; segn = N_CELL; }
        else               { idx = c2g_dst; segbase = S_G_IN;  segn = N_GENE; }
        for (int j = T; j < segn; j += 1024) sh[j] = 0;
        __syncthreads();
        const int chunk = (NEDGE + NPART - 1) / NPART;
        int e0 = blk * chunk, e1 = min(NEDGE, e0 + chunk);
        for (int e = e0 + T; e < e1; e += 1024) atomicAdd(&sh[idx[e]], 1);
        __syncthreads();
        int* pp = partial + blk * NBINS + segbase;
        for (int j = T; j < segn; j += 1024) pp[j] = sh[j];
    } else {
        const int NG = N_GENE * D, NC = N_CELL * D, NW = D * D;
        int base = (B - 4 * NPART) * 1024 + T;
        const int CH = (NG + NC) / 8;          // 8-elem chunks
        for (int c = base; c < CH; c += 64 * 1024) {
            const float* sp;
            unsigned short* dp;
            if (c < NG / 8) { sp = gene_emb + c * 8; dp = gene_bf + c * 8; }
            else { int j = (c - NG / 8) * 8; sp = cell_emb + j; dp = cell_bf + j; }
            f32x4 x0 = *(const f32x4*)sp;
            f32x4 x1 = *(const f32x4*)(sp + 4);
            ushort8v o;
            o[0] = f2bf(x0[0]); o[1] = f2bf(x0[1]);
            o[2] = f2bf(x0[2]); o[3] = f2bf(x0[3]);
            o[4] = f2bf(x1[0]); o[5] = f2bf(x1[1]);
            o[6] = f2bf(x1[2]); o[7] = f2bf(x1[3]);
            *(ushort8v*)dp = o;
        }
        for (int i = base; i < 2 * NW; i += 64 * 1024) {
            if (i < NW) {
                wt1[i] = f2bf(W_g2c[(i & 255) * D + (i >> 8)]);
            } else {
                int j = i - NW;
                wt2[j] = f2bf(W_c2g[(j & 255) * D + (j >> 8)]);
            }
        }
        // zero sg/sc for k_gemm2's atomic partial dots
        for (int i = base; i < N_GENE + N_CELL; i += 64 * 1024) {
            if (i < N_GENE) sg[i] = 0.f; else sc[i - N_GENE] = 0.f;
        }
    }
}

// Fused reduce + counting sort (no k_reduce launch). Each block recomputes,
// with k_reduce's COALESCED pattern (thread=bin grid-stride, b-loop across
// lanes coalesced — fixing R4's stride-5 mistake):
//   - dst-segment totals stot[j] + this block's exclusive rank over b<blk
//   - src-segment norms nsrcf[j]
// then LDS-scans stot -> soffs, seeds cursors = soffs + rank, scatters.
// blk==0 publishes global offs + dst-segment nrm (for k_agg).
// LDS = 60.6KB (segbuf union) -> 2 blocks/CU; 128 blocks total.
__global__ __launch_bounds__(1024) void k_scatter(
        const int* __restrict__ g2c_src, const int* __restrict__ g2c_dst,
        const int* __restrict__ c2g_src, const int* __restrict__ c2g_dst,
        const int* __restrict__ partial, float* __restrict__ nrm,
        int* __restrict__ offsC, int* __restrict__ offsG,
        int2* __restrict__ sortC, int2* __restrict__ sortG) {
    __shared__ int   segbuf[N_GENE + N_CELL];   // [0..nb): stot, [nb..nb+ns): nsrcf
    __shared__ int   srank[N_GENE];             // exclusive rank -> cursors
    __shared__ int   soffs[N_GENE + 1];
    __shared__ int   wsum[16];
    int T = threadIdx.x, blk = blockIdx.x, dir = blockIdx.y;
    const int* src  = dir ? c2g_src : g2c_src;
    const int* dst  = dir ? c2g_dst : g2c_dst;
    int seg         = dir ? S_G_IN : S_C_IN;    // dst-degree segment
    int sseg        = dir ? S_C_OUT : S_G_OUT;  // src-degree segment
    int nb          = dir ? N_GENE : N_CELL;    // dst bins
    int ns          = dir ? N_CELL : N_GENE;    // src bins
    int* goffs      = dir ? offsG : offsC;
    int2* sorted    = dir ? sortG : sortC;
    int* stot       = segbuf;
    float* nsrcf    = (float*)(segbuf + nb);

    // Phase 1a: dst totals + own rank (coalesced: thread=bin, b across lanes)
    for (int j = T; j < nb; j += 1024) {
        const int* pp = partial + seg + j;
        int tot = 0, rank = 0;
        #pragma unroll 8
        for (int b = 0; b < NPART; b++) {
            int v = pp[b * NBINS];
            tot += v;
            if (b < blk) rank += v;
        }
        stot[j] = tot;
        srank[j] = rank;
        if (blk == 0) nrm[seg + j] = rsqrtf(fmaxf((float)tot, 1.0f));
    }
    // Phase 1b: src norms (same coalesced pattern)
    for (int j = T; j < ns; j += 1024) {
        const int* pp = partial + sseg + j;
        int tot = 0;
        #pragma unroll 8
        for (int b = 0; b < NPART; b++) tot += pp[b * NBINS];
        nsrcf[j] = rsqrtf(fmaxf((float)tot, 1.0f));
    }
    __syncthreads();

    // Phase 2: exclusive scan of stot -> soffs (R7's verified scan)
    int per = (nb + 1023) >> 10;              // <=5
    int i0 = T * per, i1 = min(nb, i0 + per);
    int loc[5];
    int s = 0;
    for (int i = i0; i < i1; i++) { loc[i - i0] = s; s += stot[i]; }
    int lane = T & 63, w = T >> 6;
    int t = s;
    #pragma unroll
    for (int off = 1; off < 64; off <<= 1) {
        int u = __shfl_up(t, off);
        if (lane >= off) t += u;
    }
    if (lane == 63) wsum[w] = t;
    __syncthreads();
    if (w == 0 && lane < 16) {
        int x = wsum[lane];
        #pragma unroll
        for (int off = 1; off < 16; off <<= 1) {
            int u = __shfl_up(x, off);
            if (lane >= off) x += u;
        }
        wsum[lane] = x;
    }
    __syncthreads();
    int wbase = w ? wsum[w - 1] : 0;
    int excl = wbase + t - s;
    for (int i = i0; i < i1; i++) soffs[i] = excl + loc[i - i0];
    if (T == 1023) soffs[nb] = excl + s;
    __syncthreads();
    if (blk == 0)
        for (int j = T; j <= nb; j += 1024) goffs[j] = soffs[j];
    for (int j = T; j < nb; j += 1024) srank[j] += soffs[j];   // cursors
    __syncthreads();

    // Phase 3: scatter
    const int chunk = (NEDGE + NPART - 1) / NPART;
    int e0 = blk * chunk, e1 = min(NEDGE, e0 + chunk);
    for (int e = e0 + T; e < e1; e += 1024) {
        int d = dst[e], sv = src[e];
        float nv = nsrcf[sv];
        int pos = atomicAdd(&srank[d], 1);
        sorted[pos] = make_int2(sv, __float_as_int(nv));
    }
}

// Aggregation with paired-row 16B loads (R7-benched best): blocks 0..846
// block-per-cell (4 waves split edges, LDS pacc reduce); rest wave-per-gene.
__global__ __launch_bounds__(256) void k_agg(
        const unsigned short* __restrict__ gene_bf,
        const unsigned short* __restrict__ cell_bf,
        const int2* __restrict__ sortC, const int2* __restrict__ sortG,
        const int* __restrict__ offsC, const int* __restrict__ offsG,
        const float* __restrict__ nrm,
        unsigned short* __restrict__ aggC, unsigned short* __restrict__ aggG) {
    __shared__ int   sidx[4][64];
    __shared__ float snrm[4][64];
    __shared__ float pacc[4][256];
    int w = threadIdx.x >> 6, lane = threadIdx.x & 63;
    int half = lane >> 5, li = lane & 31;
    int B = blockIdx.x;
    bool isCell = B < N_CELL;

    int e0, e1;
    const unsigned short* emb;
    const int2* sorted;
    int node;
    if (isCell) {
        node = B;
        int f0 = offsC[node], f1 = offsC[node + 1];
        int ne = f1 - f0, nw = (ne + 3) >> 2;
        e0 = f0 + w * nw; e1 = min(f1, e0 + nw);
        emb = gene_bf; sorted = sortC;
    } else {
        node = (B - N_CELL) * 4 + w;
        if (node >= N_GENE) return;
        e0 = offsG[node]; e1 = offsG[node + 1];
        emb = cell_bf; sorted = sortG;
    }

    float acc[8];
    #pragma unroll
    for (int c = 0; c < 8; c++) acc[c] = 0.f;

    for (int base = e0; base < e1; base += 64) {
        int n = min(64, e1 - base);
        if (lane < n) {
            int2 pr = sorted[base + lane];
            sidx[w][lane] = pr.x;
            snrm[w][lane] = __int_as_float(pr.y);
        }
        // same-wave LDS write->read: program order, no barrier needed
        int i = 0;
        for (; 2 * i + 16 <= n; i += 8) {          // 8 loads in flight, 16 rows/iter
            ushort8v v[8];
            float nv[8];
            #pragma unroll
            for (int k = 0; k < 8; k++) {
                int jj = 2 * i + 2 * k + half;
                v[k] = *(const ushort8v*)&emb[sidx[w][jj] * D + li * 8];
                nv[k] = snrm[w][jj];
            }
            #pragma unroll
            for (int c = 0; c < 8; c++) {
                float s0 = 0.f;
                #pragma unroll
                for (int k = 0; k < 8; k++) s0 += bf2f(v[k][c]) * nv[k];
                acc[c] += s0;
            }
        }
        for (; 2 * i + 8 <= n; i += 4) {
            int j0 = 2 * i + half, j1 = 2 * i + 2 + half;
            int j2 = 2 * i + 4 + half, j3 = 2 * i + 6 + half;
            ushort8v v0 = *(const ushort8v*)&emb[sidx[w][j0] * D + li * 8];
            ushort8v v1 = *(const ushort8v*)&emb[sidx[w][j1] * D + li * 8];
            ushort8v v2 = *(const ushort8v*)&emb[sidx[w][j2] * D + li * 8];
            ushort8v v3 = *(const ushort8v*)&emb[sidx[w][j3] * D + li * 8];
            float n0 = snrm[w][j0], n1 = snrm[w][j1];
            float n2 = snrm[w][j2], n3 = snrm[w][j3];
            #pragma unroll
            for (int c = 0; c < 8; c++)
                acc[c] += bf2f(v0[c]) * n0 + bf2f(v1[c]) * n1 +
                          bf2f(v2[c]) * n2 + bf2f(v3[c]) * n3;
        }
        int npair = (n + 1) >> 1;
        for (; i < npair; i++) {
            int jj = 2 * i + half;
            bool ok = jj < n;
            int idx = ok ? sidx[w][jj] : sidx[w][0];
            float nv = ok ? snrm[w][jj] : 0.f;
            ushort8v v = *(const ushort8v*)&emb[idx * D + li * 8];
            #pragma unroll
            for (int c = 0; c < 8; c++) acc[c] += bf2f(v[c]) * nv;
        }
    }
    #pragma unroll
    for (int c = 0; c < 8; c++) acc[c] += __shfl_xor(acc[c], 32);

    if (isCell) {
        if (half == 0) {
            #pragma unroll
            for (int c = 0; c < 8; c++) pacc[w][li * 8 + c] = acc[c];
        }
        __syncthreads();
        int T = threadIdx.x;          // T = column
        float s2 = pacc[0][T] + pacc[1][T] + pacc[2][T] + pacc[3][T];
        aggC[node * D + T] = f2bf(s2 * nrm[S_C_IN + node]);
    } else {
        if (half == 0) {
            float ndv = nrm[S_G_IN + node];
            ushort8v o;
            #pragma unroll
            for (int c = 0; c < 8; c++) o[c] = f2bf(acc[c] * ndv);
            *(ushort8v*)&aggG[node * D + li * 8] = o;
        }
    }
}

// MFMA bf16 GEMM, N-split 4x for occupancy (verified R7): wid = (tile, quad).
// H = relu(Agg @ W + b); Wp row-dot partials accumulated via f32 atomicAdd.
__global__ __launch_bounds__(256) void k_gemm2(
        const unsigned short* __restrict__ aggC, const unsigned short* __restrict__ aggG,
        const unsigned short* __restrict__ wt1, const unsigned short* __restrict__ wt2,
        const float* __restrict__ b_g2c, const float* __restrict__ b_c2g,
        const float* __restrict__ Wp,
        float* __restrict__ hC, float* __restrict__ hG,
        float* __restrict__ sg, float* __restrict__ sc) {
    const int CT = (N_CELL + 15) / 16;   // 53
    const int GT = (N_GENE + 15) / 16;   // 298
    int wid = blockIdx.x * 4 + (threadIdx.x >> 6);
    if (wid >= (CT + GT) * 4) return;
    int tid = wid >> 2, nq = wid & 3;
    int n0 = nq * 64;
    bool isCell = tid < CT;
    int tile = isCell ? tid : tid - CT;
    int m0 = tile * 16;
    int M = isCell ? N_CELL : N_GENE;
    const unsigned short* A  = isCell ? aggC : aggG;
    const unsigned short* Wt = isCell ? wt1 : wt2;
    const float* bias = isCell ? b_g2c : b_c2g;
    const float* wp   = isCell ? Wp + D : Wp;
    float* H  = isCell ? hC : hG;
    float* sv = isCell ? sc : sg;
    int lane = threadIdx.x & 63;
    int l15 = lane & 15, quad = lane >> 4;
    int arow = m0 + l15;
    if (arow >= M) arow = M - 1;
    f32x4 acc[4];
    #pragma unroll
    for (int t = 0; t < 4; t++) acc[t] = (f32x4){0.f, 0.f, 0.f, 0.f};
    #pragma unroll
    for (int k0 = 0; k0 < D; k0 += 32) {
        short8 a = *(const short8*)&A[arow * D + k0 + quad * 8];
        #pragma unroll
        for (int t = 0; t < 4; t++) {
            short8 b = *(const short8*)&Wt[(n0 + t * 16 + l15) * D + k0 + quad * 8];
            acc[t] = __builtin_amdgcn_mfma_f32_16x16x32_bf16(a, b, acc[t], 0, 0, 0);
        }
    }
    float dot[4] = {0.f, 0.f, 0.f, 0.f};
    #pragma unroll
    for (int t = 0; t < 4; t++) {
        int col = n0 + t * 16 + l15;
        float bv = bias[col], wv = wp[col];
        #pragma unroll
        for (int r = 0; r < 4; r++) {
            int row = m0 + quad * 4 + r;
            float h = fmaxf(acc[t][r] + bv, 0.f);
            if (row < M) H[row * D + col] = h;
            dot[r] += h * wv;
        }
    }
    #pragma unroll
    for (int off = 1; off < 16; off <<= 1) {
        #pragma unroll
        for (int r = 0; r < 4; r++) dot[r] += __shfl_xor(dot[r], off);
    }
    if (l15 == 0) {
        #pragma unroll
        for (int r = 0; r < 4; r++) {
            int row = m0 + quad * 4 + r;
            if (row < M) atomicAdd(&sv[row], dot[r]);
        }
    }
}

__global__ void k_score(const int* __restrict__ dsrc, const int* __restrict__ ddst,
                        const float* __restrict__ sg, const float* __restrict__ sc,
                        const float* __restrict__ bp, float* __restrict__ out) {
    int i = blockIdx.x * blockDim.x + threadIdx.x;
    if (i < NEDGE) out[i] = sg[dsrc[i]] + sc[ddst[i]] + bp[0];
}

extern "C" void kernel_launch(void* const* d_in, const int* in_sizes, int n_in,
                              void* d_out, int out_size, void* d_ws, size_t ws_size,
                              hipStream_t stream) {
    const float* gene_emb = (const float*)d_in[0];
    const float* cell_emb = (const float*)d_in[1];
    const float* W_g2c    = (const float*)d_in[2];
    const float* b_g2c    = (const float*)d_in[3];
    const float* W_c2g    = (const float*)d_in[4];
    const float* b_c2g    = (const float*)d_in[5];
    const float* Wp       = (const float*)d_in[6];
    const float* bp       = (const float*)d_in[7];
    const int* g2c_src = (const int*)d_in[8];
    const int* g2c_dst = (const int*)d_in[9];
    const int* c2g_src = (const int*)d_in[10];
    const int* c2g_dst = (const int*)d_in[11];
    const int* dec_src = (const int*)d_in[12];
    const int* dec_dst = (const int*)d_in[13];

    int*   wsi = (int*)d_ws;
    float* wsf = (float*)d_ws;
    unsigned short* gene_bf = (unsigned short*)(wsi + A_GENE_BF);
    unsigned short* cell_bf = (unsigned short*)(wsi + A_CELL_BF);
    unsigned short* wt1     = (unsigned short*)(wsi + A_WT1_BF);
    unsigned short* wt2     = (unsigned short*)(wsi + A_WT2_BF);
    unsigned short* aggC    = (unsigned short*)(wsi + A_AGGC_BF);
    unsigned short* aggG    = (unsigned short*)(wsi + A_AGGG_BF);
    int2* sortC = (int2*)(wsi + A_SORT_C);
    int2* sortG = (int2*)(wsi + A_SORT_G);

    float* out = (float*)d_out;
    float* out_score = out;                      // [200000]
    float* out_hgene = out + NEDGE;              // [4762*256]
    float* out_hcell = out + NEDGE + N_GENE * D; // [847*256]

    // 1. segment-split hist (blocks 0..255) + vectorized cvt / W^T / zero (256..319)
    k_pre<<<4 * NPART + 64, 1024, 0, stream>>>(g2c_src, g2c_dst, c2g_src, c2g_dst,
                                               gene_emb, cell_emb, W_g2c, W_c2g,
                                               wsi + A_PART, gene_bf, cell_bf, wt1, wt2,
                                               wsf + A_SG, wsf + A_SC);
    // 2. fused reduce + counting sort (coalesced redundant column sums; no k_reduce)
    {
        dim3 grid(NPART, 2);
        k_scatter<<<grid, 1024, 0, stream>>>(g2c_src, g2c_dst, c2g_src, c2g_dst,
                                             wsi + A_PART, wsf + A_NRM,
                                             wsi + A_OFFS_C, wsi + A_OFFS_G,
                                             sortC, sortG);
    }
    // 3. aggregate: block-per-cell + wave-per-gene, paired-row 16B loads
    k_agg<<<N_CELL + (N_GENE + 3) / 4, 256, 0, stream>>>(
        gene_bf, cell_bf, sortC, sortG, wsi + A_OFFS_C, wsi + A_OFFS_G,
        wsf + A_NRM, aggC, aggG);
    // 4. MFMA GEMMs (N-split 4x) + bias + relu + atomic Wp row-dots
    {
        const int CT = (N_CELL + 15) / 16, GT = (N_GENE + 15) / 16;
        k_gemm2<<<CT + GT, 256, 0, stream>>>(aggC, aggG, wt1, wt2,
                                             b_g2c, b_c2g, Wp,
                                             out_hcell, out_hgene,
                                             wsf + A_SG, wsf + A_SC);
    }
    // 5. edge scores
    k_score<<<(NEDGE + 255) / 256, 256, 0, stream>>>(dec_src, dec_dst,
                                                     wsf + A_SG, wsf + A_SC, bp, out_score);
}

// Round 14
// 140.609 us; speedup vs baseline: 1.2769x; 1.0590x over previous
//
#include <hip/hip_runtime.h>

#define N_GENE 4762
#define N_CELL 847
#define NEDGE  200000
#define D      256
#define NPART  64     // hist/scatter chunks

typedef __attribute__((ext_vector_type(8))) short short8;            // 8 bf16
typedef __attribute__((ext_vector_type(8))) unsigned short ushort8v; // 16B load
typedef __attribute__((ext_vector_type(4))) float f32x4;

// ---- histogram segment layout (bins, concatenated) ----
#define S_G_OUT 0                      // [4762] g2c_src degrees (genes)
#define S_C_IN  (S_G_OUT + N_GENE)     // [847]  g2c_dst degrees (cells)
#define S_C_OUT (S_C_IN + N_CELL)      // [847]  c2g_src degrees (cells)
#define S_G_IN  (S_C_OUT + N_CELL)     // [4762] c2g_dst degrees (genes)
#define NBINS   (S_G_IN + N_GENE)      // 11218

#define ALIGN8(x) (((x) + 7) & ~7)

// ---- workspace layout (4-byte slots) ----
#define A_DEG      0                          // int[11218]
#define A_NRM      (A_DEG + NBINS)            // float[11218]
#define A_OFFS_C   (A_NRM + NBINS)            // int[848]
#define A_OFFS_G   (A_OFFS_C + N_CELL + 1)    // int[4763]
#define A_SORT_C   ALIGN8(A_OFFS_G + N_GENE + 1) // int2[200000]
#define A_SORT_G   (A_SORT_C + 2 * NEDGE)     // int2[200000]
#define A_PART     (A_SORT_G + 2 * NEDGE)     // int[64*11218]
#define A_SG       (A_PART + NPART * NBINS)   // float[4762]
#define A_SC       (A_SG + N_GENE)            // float[847]
// bf16 regions (ushort; slot = count/2), 16B-aligned
#define A_GENE_BF  ALIGN8(A_SC + N_CELL)
#define A_CELL_BF  ALIGN8(A_GENE_BF + N_GENE * D / 2)
#define A_WT1_BF   ALIGN8(A_CELL_BF + N_CELL * D / 2)
#define A_WT2_BF   ALIGN8(A_WT1_BF + D * D / 2)
#define A_AGGC_BF  ALIGN8(A_WT2_BF + D * D / 2)
#define A_AGGG_BF  ALIGN8(A_AGGC_BF + N_CELL * D / 2)

__device__ __forceinline__ unsigned short f2bf(float f) {
    unsigned u = __float_as_uint(f);
    u = (u + 0x7FFFu + ((u >> 16) & 1u)) >> 16;    // RNE
    return (unsigned short)u;
}
__device__ __forceinline__ float bf2f(unsigned short b) {
    return __uint_as_float(((unsigned)b) << 16);
}

// blocks 0..255: per-block LDS histograms, 4-way SEGMENT-SPLIT:
//   group s = B>>6 handles one segment (one index array), chunk = B&63.
//   LDS <= 4762 ints; one atomic per edge; partial row (B&63) is assembled
//   by the 4 groups in disjoint segments.
// blocks 256..319: bf16 conversions + W transposes + sg/sc zeroing.
__global__ __launch_bounds__(1024) void k_pre(
        const int* __restrict__ g2c_src, const int* __restrict__ g2c_dst,
        const int* __restrict__ c2g_src, const int* __restrict__ c2g_dst,
        const float* __restrict__ gene_emb, const float* __restrict__ cell_emb,
        const float* __restrict__ W_g2c, const float* __restrict__ W_c2g,
        int* __restrict__ partial,
        unsigned short* __restrict__ gene_bf, unsigned short* __restrict__ cell_bf,
        unsigned short* __restrict__ wt1, unsigned short* __restrict__ wt2,
        float* __restrict__ sg, float* __restrict__ sc) {
    __shared__ int sh[N_GENE];          // max segment size
    int B = blockIdx.x, T = threadIdx.x;
    if (B < 4 * NPART) {
        int grp = B >> 6, blk = B & (NPART - 1);
        const int* idx;
        int segbase, segn;
        if      (grp == 0) { idx = g2c_src; segbase = S_G_OUT; segn = N_GENE; }
        else if (grp == 1) { idx = g2c_dst; segbase = S_C_IN;  segn = N_CELL; }
        else if (grp == 2) { idx = c2g_src; segbase = S_C_OUT; segn = N_CELL; }
        else               { idx = c2g_dst; segbase = S_G_IN;  segn = N_GENE; }
        for (int j = T; j < segn; j += 1024) sh[j] = 0;
        __syncthreads();
        const int chunk = (NEDGE + NPART - 1) / NPART;
        int e0 = blk * chunk, e1 = min(NEDGE, e0 + chunk);
        for (int e = e0 + T; e < e1; e += 1024) atomicAdd(&sh[idx[e]], 1);
        __syncthreads();
        int* pp = partial + blk * NBINS + segbase;
        for (int j = T; j < segn; j += 1024) pp[j] = sh[j];
    } else {
        const int NG = N_GENE * D, NC = N_CELL * D, NW = D * D;
        const int total = NG + NC + 2 * NW;
        for (int i = (B - 4 * NPART) * 1024 + T; i < total; i += 64 * 1024) {
            if (i < NG) {
                gene_bf[i] = f2bf(gene_emb[i]);
            } else if (i < NG + NC) {
                int j = i - NG;
                cell_bf[j] = f2bf(cell_emb[j]);
            } else if (i < NG + NC + NW) {
                int j = i - NG - NC;
                wt1[j] = f2bf(W_g2c[(j & 255) * D + (j >> 8)]);
            } else {
                int j = i - NG - NC - NW;
                wt2[j] = f2bf(W_c2g[(j & 255) * D + (j >> 8)]);
            }
        }
        // zero sg/sc for k_gemm2's atomic partial dots
        for (int i = (B - 4 * NPART) * 1024 + T; i < N_GENE + N_CELL; i += 64 * 1024) {
            if (i < N_GENE) sg[i] = 0.f; else sc[i - N_GENE] = 0.f;
        }
    }
}

// deg[j] = sum_b partial[b][j]; partial[b][j] := exclusive prefix over b;
// nrm[j] = rsqrt(max(deg,1)). Thread=bin; each b-iteration is coalesced.
__global__ void k_reduce(int* __restrict__ partial, int* __restrict__ deg,
                         float* __restrict__ nrm) {
    int j = blockIdx.x * blockDim.x + threadIdx.x;
    if (j < NBINS) {
        int s = 0;
        #pragma unroll
        for (int b0 = 0; b0 < NPART; b0 += 32) {
            int t[32];
            #pragma unroll
            for (int u = 0; u < 32; u++) t[u] = partial[(b0 + u) * NBINS + j];
            #pragma unroll
            for (int u = 0; u < 32; u++) { partial[(b0 + u) * NBINS + j] = s; s += t[u]; }
        }
        deg[j] = s;
        nrm[j] = rsqrtf(fmaxf((float)s, 1.0f));
    }
}

// Deterministic counting sort; each block recomputes the CSR-offset scan of its
// direction's degree segment in LDS, seeds cursors with offs+base_rank,
// places int2{src, norm_src}. grid=(NPART, 2). (verified R0 code)
__global__ __launch_bounds__(1024) void k_scatter(
        const int* __restrict__ g2c_src, const int* __restrict__ g2c_dst,
        const int* __restrict__ c2g_src, const int* __restrict__ c2g_dst,
        const int* __restrict__ deg, const int* __restrict__ partial,
        const float* __restrict__ nrm,
        int* __restrict__ offsC, int* __restrict__ offsG,
        int2* __restrict__ sortC, int2* __restrict__ sortG) {
    __shared__ int soffs[N_GENE + 1];
    __shared__ int scur[N_GENE];
    __shared__ int wsum[16];
    int T = threadIdx.x, blk = blockIdx.x, dir = blockIdx.y;
    const int* src  = dir ? c2g_src : g2c_src;
    const int* dst  = dir ? c2g_dst : g2c_dst;
    const int* dgs  = dir ? deg + S_G_IN : deg + S_C_IN;
    const float* nsv = dir ? nrm + S_C_OUT : nrm + S_G_OUT;
    int seg         = dir ? S_G_IN : S_C_IN;
    int nb          = dir ? N_GENE : N_CELL;
    int* goffs      = dir ? offsG : offsC;
    int2* sorted    = dir ? sortG : sortC;
    int per = (nb + 1023) >> 10;              // <=5
    int i0 = T * per, i1 = min(nb, i0 + per);
    int loc[5];
    int s = 0;
    for (int i = i0; i < i1; i++) { loc[i - i0] = s; s += dgs[i]; }
    int lane = T & 63, w = T >> 6;
    int t = s;
    #pragma unroll
    for (int off = 1; off < 64; off <<= 1) {
        int u = __shfl_up(t, off);
        if (lane >= off) t += u;
    }
    if (lane == 63) wsum[w] = t;
    __syncthreads();
    if (w == 0 && lane < 16) {
        int x = wsum[lane];
        #pragma unroll
        for (int off = 1; off < 16; off <<= 1) {
            int u = __shfl_up(x, off);
            if (lane >= off) x += u;
        }
        wsum[lane] = x;
    }
    __syncthreads();
    int wbase = w ? wsum[w - 1] : 0;
    int excl = wbase + t - s;
    for (int i = i0; i < i1; i++) soffs[i] = excl + loc[i - i0];
    if (T == 1023) soffs[nb] = excl + s;
    __syncthreads();
    if (blk == 0)
        for (int j = T; j <= nb; j += 1024) goffs[j] = soffs[j];
    const int* basep = partial + blk * NBINS + seg;
    for (int j = T; j < nb; j += 1024) scur[j] = soffs[j] + basep[j];
    __syncthreads();
    const int chunk = (NEDGE + NPART - 1) / NPART;
    int e0 = blk * chunk, e1 = min(NEDGE, e0 + chunk);
    for (int e = e0 + T; e < e1; e += 1024) {
        int d = dst[e], sv = src[e];
        float nv = nsv[sv];
        int pos = atomicAdd(&scur[d], 1);
        sorted[pos] = make_int2(sv, __float_as_int(nv));
    }
}

// Aggregation with paired-row 16B loads (verified), 8-deep steady-state loop.
__global__ __launch_bounds__(256) void k_agg(
        const unsigned short* __restrict__ gene_bf,
        const unsigned short* __restrict__ cell_bf,
        const int2* __restrict__ sortC, const int2* __restrict__ sortG,
        const int* __restrict__ offsC, const int* __restrict__ offsG,
        const float* __restrict__ nrm,
        unsigned short* __restrict__ aggC, unsigned short* __restrict__ aggG) {
    __shared__ int   sidx[4][64];
    __shared__ float snrm[4][64];
    __shared__ float pacc[4][256];
    int w = threadIdx.x >> 6, lane = threadIdx.x & 63;
    int half = lane >> 5, li = lane & 31;
    int B = blockIdx.x;
    bool isCell = B < N_CELL;

    int e0, e1;
    const unsigned short* emb;
    const int2* sorted;
    int node;
    if (isCell) {
        node = B;
        int f0 = offsC[node], f1 = offsC[node + 1];
        int ne = f1 - f0, nw = (ne + 3) >> 2;
        e0 = f0 + w * nw; e1 = min(f1, e0 + nw);
        emb = gene_bf; sorted = sortC;
    } else {
        node = (B - N_CELL) * 4 + w;
        if (node >= N_GENE) return;
        e0 = offsG[node]; e1 = offsG[node + 1];
        emb = cell_bf; sorted = sortG;
    }

    float acc[8];
    #pragma unroll
    for (int c = 0; c < 8; c++) acc[c] = 0.f;

    for (int base = e0; base < e1; base += 64) {
        int n = min(64, e1 - base);
        if (lane < n) {
            int2 pr = sorted[base + lane];
            sidx[w][lane] = pr.x;
            snrm[w][lane] = __int_as_float(pr.y);
        }
        // same-wave LDS write->read: program order, no barrier needed
        int i = 0;
        for (; 2 * i + 16 <= n; i += 8) {          // 8 loads in flight, 16 rows/iter
            ushort8v v[8];
            float nv[8];
            #pragma unroll
            for (int k = 0; k < 8; k++) {
                int jj = 2 * i + 2 * k + half;
                v[k] = *(const ushort8v*)&emb[sidx[w][jj] * D + li * 8];
                nv[k] = snrm[w][jj];
            }
            #pragma unroll
            for (int c = 0; c < 8; c++) {
                float s0 = 0.f;
                #pragma unroll
                for (int k = 0; k < 8; k++) s0 += bf2f(v[k][c]) * nv[k];
                acc[c] += s0;
            }
        }
        for (; 2 * i + 8 <= n; i += 4) {
            int j0 = 2 * i + half, j1 = 2 * i + 2 + half;
            int j2 = 2 * i + 4 + half, j3 = 2 * i + 6 + half;
            ushort8v v0 = *(const ushort8v*)&emb[sidx[w][j0] * D + li * 8];
            ushort8v v1 = *(const ushort8v*)&emb[sidx[w][j1] * D + li * 8];
            ushort8v v2 = *(const ushort8v*)&emb[sidx[w][j2] * D + li * 8];
            ushort8v v3 = *(const ushort8v*)&emb[sidx[w][j3] * D + li * 8];
            float n0 = snrm[w][j0], n1 = snrm[w][j1];
            float n2 = snrm[w][j2], n3 = snrm[w][j3];
            #pragma unroll
            for (int c = 0; c < 8; c++)
                acc[c] += bf2f(v0[c]) * n0 + bf2f(v1[c]) * n1 +
                          bf2f(v2[c]) * n2 + bf2f(v3[c]) * n3;
        }
        int npair = (n + 1) >> 1;
        for (; i < npair; i++) {
            int jj = 2 * i + half;
            bool ok = jj < n;
            int idx = ok ? sidx[w][jj] : sidx[w][0];
            float nv = ok ? snrm[w][jj] : 0.f;
            ushort8v v = *(const ushort8v*)&emb[idx * D + li * 8];
            #pragma unroll
            for (int c = 0; c < 8; c++) acc[c] += bf2f(v[c]) * nv;
        }
    }
    #pragma unroll
    for (int c = 0; c < 8; c++) acc[c] += __shfl_xor(acc[c], 32);

    if (isCell) {
        if (half == 0) {
            #pragma unroll
            for (int c = 0; c < 8; c++) pacc[w][li * 8 + c] = acc[c];
        }
        __syncthreads();
        int T = threadIdx.x;          // T = column
        float s2 = pacc[0][T] + pacc[1][T] + pacc[2][T] + pacc[3][T];
        aggC[node * D + T] = f2bf(s2 * nrm[S_C_IN + node]);
    } else {
        if (half == 0) {
            float ndv = nrm[S_G_IN + node];
            ushort8v o;
            #pragma unroll
            for (int c = 0; c < 8; c++) o[c] = f2bf(acc[c] * ndv);
            *(ushort8v*)&aggG[node * D + li * 8] = o;
        }
    }
}

// MFMA bf16 GEMM, N-split 4x for occupancy: wid = (tile, 64-col quadrant).
// H = relu(Agg @ W + b); Wp row-dot partials accumulated via f32 atomicAdd
// into pre-zeroed sg/sc.
__global__ __launch_bounds__(256) void k_gemm2(
        const unsigned short* __restrict__ aggC, const unsigned short* __restrict__ aggG,
        const unsigned short* __restrict__ wt1, const unsigned short* __restrict__ wt2,
        const float* __restrict__ b_g2c, const float* __restrict__ b_c2g,
        const float* __restrict__ Wp,
        float* __restrict__ hC, float* __restrict__ hG,
        float* __restrict__ sg, float* __restrict__ sc) {
    const int CT = (N_CELL + 15) / 16;   // 53
    const int GT = (N_GENE + 15) / 16;   // 298
    int wid = blockIdx.x * 4 + (threadIdx.x >> 6);
    if (wid >= (CT + GT) * 4) return;
    int tid = wid >> 2, nq = wid & 3;
    int n0 = nq * 64;
    bool isCell = tid < CT;
    int tile = isCell ? tid : tid - CT;
    int m0 = tile * 16;
    int M = isCell ? N_CELL : N_GENE;
    const unsigned short* A  = isCell ? aggC : aggG;
    const unsigned short* Wt = isCell ? wt1 : wt2;
    const float* bias = isCell ? b_g2c : b_c2g;
    const float* wp   = isCell ? Wp + D : Wp;
    float* H  = isCell ? hC : hG;
    float* sv = isCell ? sc : sg;
    int lane = threadIdx.x & 63;
    int l15 = lane & 15, quad = lane >> 4;
    int arow = m0 + l15;
    if (arow >= M) arow = M - 1;
    f32x4 acc[4];
    #pragma unroll
    for (int t = 0; t < 4; t++) acc[t] = (f32x4){0.f, 0.f, 0.f, 0.f};
    #pragma unroll
    for (int k0 = 0; k0 < D; k0 += 32) {
        short8 a = *(const short8*)&A[arow * D + k0 + quad * 8];
        #pragma unroll
        for (int t = 0; t < 4; t++) {
            short8 b = *(const short8*)&Wt[(n0 + t * 16 + l15) * D + k0 + quad * 8];
            acc[t] = __builtin_amdgcn_mfma_f32_16x16x32_bf16(a, b, acc[t], 0, 0, 0);
        }
    }
    float dot[4] = {0.f, 0.f, 0.f, 0.f};
    #pragma unroll
    for (int t = 0; t < 4; t++) {
        int col = n0 + t * 16 + l15;
        float bv = bias[col], wv = wp[col];
        #pragma unroll
        for (int r = 0; r < 4; r++) {
            int row = m0 + quad * 4 + r;
            float h = fmaxf(acc[t][r] + bv, 0.f);
            if (row < M) H[row * D + col] = h;
            dot[r] += h * wv;
        }
    }
    #pragma unroll
    for (int off = 1; off < 16; off <<= 1) {
        #pragma unroll
        for (int r = 0; r < 4; r++) dot[r] += __shfl_xor(dot[r], off);
    }
    if (l15 == 0) {
        #pragma unroll
        for (int r = 0; r < 4; r++) {
            int row = m0 + quad * 4 + r;
            if (row < M) atomicAdd(&sv[row], dot[r]);
        }
    }
}

__global__ void k_score(const int* __restrict__ dsrc, const int* __restrict__ ddst,
                        const float* __restrict__ sg, const float* __restrict__ sc,
                        const float* __restrict__ bp, float* __restrict__ out) {
    int i = blockIdx.x * blockDim.x + threadIdx.x;
    if (i < NEDGE) out[i] = sg[dsrc[i]] + sc[ddst[i]] + bp[0];
}

extern "C" void kernel_launch(void* const* d_in, const int* in_sizes, int n_in,
                              void* d_out, int out_size, void* d_ws, size_t ws_size,
                              hipStream_t stream) {
    const float* gene_emb = (const float*)d_in[0];
    const float* cell_emb = (const float*)d_in[1];
    const float* W_g2c    = (const float*)d_in[2];
    const float* b_g2c    = (const float*)d_in[3];
    const float* W_c2g    = (const float*)d_in[4];
    const float* b_c2g    = (const float*)d_in[5];
    const float* Wp       = (const float*)d_in[6];
    const float* bp       = (const float*)d_in[7];
    const int* g2c_src = (const int*)d_in[8];
    const int* g2c_dst = (const int*)d_in[9];
    const int* c2g_src = (const int*)d_in[10];
    const int* c2g_dst = (const int*)d_in[11];
    const int* dec_src = (const int*)d_in[12];
    const int* dec_dst = (const int*)d_in[13];

    int*   wsi = (int*)d_ws;
    float* wsf = (float*)d_ws;
    unsigned short* gene_bf = (unsigned short*)(wsi + A_GENE_BF);
    unsigned short* cell_bf = (unsigned short*)(wsi + A_CELL_BF);
    unsigned short* wt1     = (unsigned short*)(wsi + A_WT1_BF);
    unsigned short* wt2     = (unsigned short*)(wsi + A_WT2_BF);
    unsigned short* aggC    = (unsigned short*)(wsi + A_AGGC_BF);
    unsigned short* aggG    = (unsigned short*)(wsi + A_AGGG_BF);
    int2* sortC = (int2*)(wsi + A_SORT_C);
    int2* sortG = (int2*)(wsi + A_SORT_G);

    float* out = (float*)d_out;
    float* out_score = out;                      // [200000]
    float* out_hgene = out + NEDGE;              // [4762*256]
    float* out_hcell = out + NEDGE + N_GENE * D; // [847*256]

    // 1. segment-split hist (blocks 0..255) + bf16 cvt / W^T / sg,sc zero (256..319)
    k_pre<<<4 * NPART + 64, 1024, 0, stream>>>(g2c_src, g2c_dst, c2g_src, c2g_dst,
                                               gene_emb, cell_emb, W_g2c, W_c2g,
                                               wsi + A_PART, gene_bf, cell_bf, wt1, wt2,
                                               wsf + A_SG, wsf + A_SC);
    // 2. reduce partials -> deg, nrm; partial := per-block exclusive base ranks
    k_reduce<<<(NBINS + 255) / 256, 256, 0, stream>>>(wsi + A_PART, wsi + A_DEG,
                                                      wsf + A_NRM);
    // 3. counting sort (per-block LDS offset scan; publishes global offs)
    {
        dim3 grid(NPART, 2);
        k_scatter<<<grid, 1024, 0, stream>>>(g2c_src, g2c_dst, c2g_src, c2g_dst,
                                             wsi + A_DEG, wsi + A_PART, wsf + A_NRM,
                                             wsi + A_OFFS_C, wsi + A_OFFS_G,
                                             sortC, sortG);
    }
    // 4. aggregate: block-per-cell + wave-per-gene, paired-row 16B loads
    k_agg<<<N_CELL + (N_GENE + 3) / 4, 256, 0, stream>>>(
        gene_bf, cell_bf, sortC, sortG, wsi + A_OFFS_C, wsi + A_OFFS_G,
        wsf + A_NRM, aggC, aggG);
    // 5. MFMA GEMMs (N-split 4x) + bias + relu + atomic Wp row-dots
    {
        const int CT = (N_CELL + 15) / 16, GT = (N_GENE + 15) / 16;
        k_gemm2<<<CT + GT, 256, 0, stream>>>(aggC, aggG, wt1, wt2,
                                             b_g2c, b_c2g, Wp,
                                             out_hcell, out_hgene,
                                             wsf + A_SG, wsf + A_SC);
    }
    // 6. edge scores
    k_score<<<(NEDGE + 255) / 256, 256, 0, stream>>>(dec_src, dec_dst,
                                                     wsf + A_SG, wsf + A_SC, bp, out_score);
}